// Round 17
// baseline (248.674 us; speedup 1.0000x reference)
//
#include <hip/hip_runtime.h>

typedef __attribute__((ext_vector_type(8))) short  bf16x8;
typedef __attribute__((ext_vector_type(8))) unsigned short u16x8;
typedef __attribute__((ext_vector_type(4))) float  f32x4;

constexpr int S    = 4096;
constexpr int NR   = 4093;
constexpr int KAPP = 10000;
constexpr int EAPP = 256;
constexpr int ETIM = 64;
constexpr int DIN  = 320;
constexpr int NDEC = 10000;
constexpr int NSK  = 8;           // split-K slices (== XCD count)
constexpr int KCH  = 1248;        // 39 steps x 32; 8*1248 = 9984, all in-bounds
constexpr int NS   = 39;          // K-steps per block
constexpr int TAILK= 9984;        // 16-wide k-tail handled in k_reduce
constexpr int KPAD = 10240;       // Bpp baked k-extent (zeros past 10000)

__device__ inline unsigned short f2bf(float f) {
    unsigned u = __float_as_uint(f);
    u += 0x7fffu + ((u >> 16) & 1u);      // RTN-even
    return (unsigned short)(u >> 16);
}
__device__ inline float bf2f(unsigned short h) {
    return __uint_as_float(((unsigned)h) << 16);
}
__device__ inline u16x8 pack8(f32x4 a, f32x4 b) {
    u16x8 v;
    v[0]=f2bf(a.x); v[1]=f2bf(a.y); v[2]=f2bf(a.z); v[3]=f2bf(a.w);
    v[4]=f2bf(b.x); v[5]=f2bf(b.y); v[6]=f2bf(b.z); v[7]=f2bf(b.w);
    return v;
}
__device__ inline bf16x8 as_bf(u16x8 v) {
    union { u16x8 u; bf16x8 b; } c; c.u = v; return c.b;
}

// -------------------------------------------------- fp32 -> bf16 bulk convert
__global__ __launch_bounds__(256) void k_cvt_bf16(
    const float* __restrict__ in, unsigned short* __restrict__ out, int n8)
{
    int id = blockIdx.x * 256 + threadIdx.x;
    if (id >= n8) return;
    const float* p = in + (size_t)id * 8;
    f32x4 a = *reinterpret_cast<const f32x4*>(p);
    f32x4 b = *reinterpret_cast<const f32x4*>(p + 4);
    *reinterpret_cast<u16x8*>(out + (size_t)id * 8) = pack8(a, b);
}

// ------------- bake emb_app_w into per-gstep LDS images for global_load_lds:
// Bpp[gstep][chunk c][8 halves], c = ck*256 + n -> B^T[n][32*gstep + ck*8 .. +7]
__global__ __launch_bounds__(256) void k_bake_appw(
    const float* __restrict__ B, unsigned short* __restrict__ Bpp)
{
    __shared__ float T[64][68];
    const int kt = blockIdx.x * 64, nt = blockIdx.y * 64;
    const int tid = threadIdx.x;
    #pragma unroll
    for (int i = 0; i < 4; ++i) {
        int c = tid + (i << 8);
        int k = c >> 4, n4 = (c & 15) << 2;
        f32x4 v = {0.f, 0.f, 0.f, 0.f};
        if (kt + k < KAPP)
            v = *reinterpret_cast<const f32x4*>(&B[(size_t)(kt + k) * EAPP + nt + n4]);
        *reinterpret_cast<f32x4*>(&T[k][n4]) = v;
    }
    __syncthreads();
    #pragma unroll
    for (int i = 0; i < 2; ++i) {
        int c = tid + (i << 8);              // 0..511
        int ln = c & 63, lc = c >> 6;        // local n, local 8k-chunk
        int t = (kt >> 5) + (lc >> 2), ck = lc & 3;
        u16x8 v;
        #pragma unroll
        for (int h = 0; h < 8; ++h) v[h] = f2bf(T[(lc << 3) + h][ln]);
        *reinterpret_cast<u16x8*>(
            &Bpp[((size_t)t * 1024 + (ck << 8) + nt + ln) * 8]) = v;
    }
}

// ---------------------------------------------------------------- embeddings
__global__ __launch_bounds__(256) void k_embed_tim(
    const int* __restrict__ tim, const float* __restrict__ emb_tim,
    unsigned short* __restrict__ xb)
{
    int r = blockIdx.x * 4 + (threadIdx.x >> 6);
    int e = threadIdx.x & 63;
    xb[(size_t)r * DIN + EAPP + e] = f2bf(emb_tim[tim[r] * ETIM + e]);
}
__global__ __launch_bounds__(256) void k_embed_ptim(
    const int* __restrict__ ptim, const float* __restrict__ emb_tim,
    unsigned short* __restrict__ yb)
{
    int r = blockIdx.x * 4 + (threadIdx.x >> 6);
    int e = threadIdx.x & 63;
    if (r < NR) yb[(size_t)r * DIN + EAPP + e] = f2bf(emb_tim[ptim[r] * ETIM + e]);
}

// ---------- app GEMM: split-K x8, tile 32x256.
// B: global_load_lds into 3x16KB buffers, counted vmcnt(8) (never 0 in main
// loop), ONE raw s_barrier/phase — loads stay 2 phases in flight.
// A: per-wave direct-to-register, 3 named sets cycling with the 3-phase
// period (static indices). 48KB LDS -> 3 blocks/CU.
__global__ __launch_bounds__(256, 3) void k_app(
    const float* __restrict__ A, const unsigned short* __restrict__ Bpp,
    float* __restrict__ part)
{
    __shared__ unsigned short Bs[3][8192];   // 3 x 16 KB
    const int tid = threadIdx.x, lane = tid & 63, w = tid >> 6;
    const int ks = blockIdx.x, bm = blockIdx.y << 5;  // flat%8==ks -> XCD-pinned
    const int wc = w << 6, rl = lane & 15, kq = lane >> 4;
    const int kO = ks * KCH;
    const unsigned short* gB = Bpp + ((size_t)(ks * NS) << 13) + (lane << 3);

    f32x4 acc[2][4];
    #pragma unroll
    for (int i = 0; i < 2; ++i)
        #pragma unroll
        for (int j = 0; j < 4; ++j) acc[i][j] = (f32x4){0.f, 0.f, 0.f, 0.f};

    f32x4 a0[2][2], a1[2][2], a2[2][2];   // 3 named A-sets (static only)

#define STAGEB(T, BUF) do {                                                     \
    const unsigned short* sB_ = gB + ((size_t)(T) << 13);                       \
    _Pragma("unroll")                                                           \
    for (int q = 0; q < 4; ++q)                                                 \
        __builtin_amdgcn_global_load_lds(                                       \
            (const __attribute__((address_space(1))) void*)(sB_ +               \
                ((((w << 2) + q)) << 9)),                                       \
            (__attribute__((address_space(3))) void*)(                          \
                &Bs[BUF][(((w << 2) + q)) << 9]),                               \
            16, 0, 0);                                                          \
} while (0)

#define LOADA(T, SET) do {                                                      \
    _Pragma("unroll")                                                           \
    for (int i = 0; i < 2; ++i) {                                               \
        const float* p_ = A + (size_t)(bm + (i << 4) + rl) * KAPP               \
                            + kO + ((T) << 5) + (kq << 3);                      \
        SET[i][0] = *reinterpret_cast<const f32x4*>(p_);                        \
        SET[i][1] = *reinterpret_cast<const f32x4*>(p_ + 4);                    \
    }                                                                           \
} while (0)

#define COMPUTE(SET, BUF) do {                                                  \
    bf16x8 af_[2], bf_[4];                                                      \
    _Pragma("unroll")                                                           \
    for (int i = 0; i < 2; ++i)                                                 \
        af_[i] = as_bf(pack8(SET[i][0], SET[i][1]));                            \
    _Pragma("unroll")                                                           \
    for (int j = 0; j < 4; ++j)                                                 \
        bf_[j] = *reinterpret_cast<const bf16x8*>(                              \
            &Bs[BUF][((kq << 8) + wc + (j << 4) + rl) << 3]);                   \
    _Pragma("unroll")                                                           \
    for (int i = 0; i < 2; ++i)                                                 \
        _Pragma("unroll")                                                       \
        for (int j = 0; j < 4; ++j)                                             \
            acc[i][j] = __builtin_amdgcn_mfma_f32_16x16x32_bf16(                \
                af_[i], bf_[j], acc[i][j], 0, 0, 0);                            \
} while (0)

// phase T: wait B(T) landed (retain A(T)+B(T+1) = 8), barrier, then issue
// A(T+1) and B(T+2) before computing T. Stage target (T+2)%3 = (T-1)%3,
// whose readers (phase T-1) precede this barrier in every wave.
#define PH(T, ACUR, ANXT, BUF, BUF2) do {                                       \
    asm volatile("s_waitcnt vmcnt(8)" ::: "memory");                            \
    __builtin_amdgcn_s_barrier();                                               \
    __builtin_amdgcn_sched_barrier(0);                                          \
    LOADA((T) + 1, ANXT);                                                       \
    STAGEB((T) + 2, BUF2);                                                      \
    __builtin_amdgcn_sched_barrier(0);                                          \
    COMPUTE(ACUR, BUF);                                                         \
} while (0)

    // prologue: B(0), A(0), B(1) — this order makes vmcnt(8) force B(0)
    STAGEB(0, 0);
    LOADA(0, a0);
    STAGEB(1, 1);
    for (int it = 0; it < 12; ++it) {        // phases 0..35
        PH(it * 3 + 0, a0, a1, 0, 2);
        PH(it * 3 + 1, a1, a2, 1, 0);
        PH(it * 3 + 2, a2, a0, 2, 1);
    }
    PH(36, a0, a1, 0, 2);                    // stages B(38), loads A(37)
    // phase 37: no B(39); vmcnt(8) retains A(37)+B(38), forces B(37)
    asm volatile("s_waitcnt vmcnt(8)" ::: "memory");
    __builtin_amdgcn_s_barrier();
    __builtin_amdgcn_sched_barrier(0);
    LOADA(38, a2);
    __builtin_amdgcn_sched_barrier(0);
    COMPUTE(a1, 1);
    // phase 38: vmcnt(4) retains A(38), forces B(38)
    asm volatile("s_waitcnt vmcnt(4)" ::: "memory");
    __builtin_amdgcn_s_barrier();
    COMPUTE(a2, 2);
#undef STAGEB
#undef LOADA
#undef COMPUTE
#undef PH

    float* P = part + ((size_t)ks * S + bm) * EAPP;
    const int rq = kq << 2;
    #pragma unroll
    for (int i = 0; i < 2; ++i)
        #pragma unroll
        for (int j = 0; j < 4; ++j) {
            int col = wc + j * 16 + rl;
            #pragma unroll
            for (int q = 0; q < 4; ++q)
                __builtin_nontemporal_store(acc[i][j][q],
                    &P[(size_t)(i * 16 + rq + q) * EAPP + col]);
        }
}

// ------------- reduce split-K partials + 16-wide k-tail -> xb[:,0:256]
__global__ __launch_bounds__(256) void k_reduce_app(
    const float* __restrict__ part, const float* __restrict__ A,
    const unsigned short* __restrict__ Bpp, unsigned short* __restrict__ xb)
{
    int id = blockIdx.x * 256 + threadIdx.x;   // 262144 = 4096*64
    int row = id >> 6, c4 = (id & 63) << 2;
    f32x4 s = {0.f, 0.f, 0.f, 0.f};
    #pragma unroll
    for (int sl = 0; sl < NSK; ++sl) {
        f32x4 v = __builtin_nontemporal_load(reinterpret_cast<const f32x4*>(
            &part[((size_t)sl * S + row) * EAPP + c4]));
        s.x += v.x; s.y += v.y; s.z += v.z; s.w += v.w;
    }
    // tail k = 9984..9999 (gstep 312 of Bpp holds it, zeros past 10000)
    #pragma unroll
    for (int ck = 0; ck < 2; ++ck) {
        f32x4 a0 = *reinterpret_cast<const f32x4*>(&A[(size_t)row * KAPP + TAILK + (ck << 3)]);
        f32x4 a1 = *reinterpret_cast<const f32x4*>(&A[(size_t)row * KAPP + TAILK + (ck << 3) + 4]);
        float av[8] = {a0.x, a0.y, a0.z, a0.w, a1.x, a1.y, a1.z, a1.w};
        #pragma unroll
        for (int e = 0; e < 4; ++e) {
            u16x8 bv = *reinterpret_cast<const u16x8*>(
                &Bpp[((size_t)(312 * 1024 + (ck << 8) + c4 + e)) * 8]);
            float t = 0.f;
            #pragma unroll
            for (int h = 0; h < 8; ++h) t = fmaf(av[h], bf2f(bv[h]), t);
            s[e] += t;
        }
    }
    unsigned short* o = &xb[(size_t)row * DIN + c4];
    o[0] = f2bf(s.x); o[1] = f2bf(s.y); o[2] = f2bf(s.z); o[3] = f2bf(s.w);
}

// ------------------------------------------------- attention score + pooling
__global__ __launch_bounds__(256) void k_score(
    const unsigned short* __restrict__ xb, const float* __restrict__ W,
    float* __restrict__ s)
{
    int wv = threadIdx.x >> 6, lane = threadIdx.x & 63;
    int m = blockIdx.x * 4 + wv;
    float sum = 0.f;
    #pragma unroll
    for (int i = 0; i < 5; ++i) {
        int k = lane + (i << 6);
        sum += bf2f(xb[(size_t)m * DIN + k]) * W[k];
    }
    #pragma unroll
    for (int off = 32; off; off >>= 1) sum += __shfl_down(sum, off);
    if (lane == 0) s[m] = sum;
}

__global__ void k_pooled(
    const unsigned short* __restrict__ xb, const float* __restrict__ s,
    const float* __restrict__ attn_b, unsigned short* __restrict__ pooledb)
{
    int n = blockIdx.x, d = threadIdx.x;
    float h[4], den = 0.f;
    #pragma unroll
    for (int f = 0; f < 4; ++f) {
        h[f] = tanhf(s[n + f] + attn_b[f]);
        den += fabsf(h[f]);
    }
    float inv = 1.f / den, p = 0.f;
    #pragma unroll
    for (int f = 0; f < 4; ++f)
        p = fmaf(h[f] * inv, bf2f(xb[(size_t)(n + f) * DIN + d]), p);
    pooledb[(size_t)n * DIN + d] = f2bf(p);
}

// ------------------- NT GEMM, K=320 (round-10 verified): A staged once in
// chunked LDS, B depth-2 prefetch, bn-FASTEST block order, NT stores.
template<int EPI>
__global__ __launch_bounds__(256, 4) void k_nt320(
    const unsigned short* __restrict__ A, const unsigned short* __restrict__ B,
    int Nb, int Mlim,
    const float* __restrict__ bias,
    const float* __restrict__ emb_uid, const int* __restrict__ uid,
    void* __restrict__ Cout, int ldc)
{
    __shared__ unsigned short As[40 * 64 * 8];     // ((ck*64+row)*8), 40960 B
    const int tid = threadIdx.x, lane = tid & 63, w = tid >> 6;
    const int qx = gridDim.x >> 3;                 // nwg % 8 == 0 always here
    const int swz = (blockIdx.x & 7) * qx + (blockIdx.x >> 3);
    const int nbn = (Nb + 255) >> 8;               // bn-groups (dec: 40, fc: 1)
    const int bm = (swz / nbn) << 6, bn = (swz % nbn) << 8;   // bn FASTEST
    const int rl = lane & 15, kq = lane >> 4;
    const int wc = w << 6;

    {   // stage A-tile (64 x 320 bf16 = 40 KB) once, chunked layout
        const int row = tid >> 2, c0 = tid & 3;
        const unsigned short* src = A + (size_t)(bm + row) * DIN;
        #pragma unroll
        for (int t = 0; t < 10; ++t) {
            int ck = c0 + (t << 2);
            *reinterpret_cast<u16x8*>(&As[((ck << 6) + row) << 3]) =
                *reinterpret_cast<const u16x8*>(src + (ck << 3));
        }
    }
    __syncthreads();

    f32x4 acc[4][4];
    #pragma unroll
    for (int i = 0; i < 4; ++i)
        #pragma unroll
        for (int j = 0; j < 4; ++j) acc[i][j] = (f32x4){0.f, 0.f, 0.f, 0.f};

    u16x8 b0[4], b1[4];
#define LOADB(DST, KSN) do {                                                    \
    const int kg_ = ((KSN) << 5) + (kq << 3);                                   \
    _Pragma("unroll")                                                           \
    for (int j = 0; j < 4; ++j) {                                               \
        int brow = bn + wc + j * 16 + rl;                                       \
        u16x8 v_ = {0,0,0,0,0,0,0,0};                                           \
        if (brow < Nb)                                                          \
            v_ = *reinterpret_cast<const u16x8*>(&B[(size_t)brow * DIN + kg_]); \
        DST[j] = v_;                                                            \
    }                                                                           \
} while (0)

#define STEPNT(BARR, KSN) do {                                                  \
    const int ckb_ = (((KSN) << 2) + kq) << 6;                                  \
    bf16x8 af_[4];                                                              \
    _Pragma("unroll")                                                           \
    for (int i = 0; i < 4; ++i)                                                 \
        af_[i] = *reinterpret_cast<const bf16x8*>(                              \
            &As[(ckb_ + i * 16 + rl) << 3]);                                    \
    _Pragma("unroll")                                                           \
    for (int i = 0; i < 4; ++i)                                                 \
        _Pragma("unroll")                                                       \
        for (int j = 0; j < 4; ++j)                                             \
            acc[i][j] = __builtin_amdgcn_mfma_f32_16x16x32_bf16(                \
                af_[i], as_bf(BARR[j]), acc[i][j], 0, 0, 0);                     \
} while (0)

    LOADB(b0, 0);
    LOADB(b1, 1);
    #pragma unroll
    for (int p = 0; p < 5; ++p) {
        STEPNT(b0, 2 * p);
        if (2 * p + 2 < 10) LOADB(b0, 2 * p + 2);
        STEPNT(b1, 2 * p + 1);
        if (2 * p + 3 < 10) LOADB(b1, 2 * p + 3);
    }
#undef LOADB
#undef STEPNT

    const int rq = kq << 2;
    if (EPI == 1) {
        unsigned short* C = (unsigned short*)Cout;
        const float* us = emb_uid + (size_t)uid[0] * EAPP;
        #pragma unroll
        for (int j = 0; j < 4; ++j) {
            int col = bn + wc + j * 16 + rl;
            if (col >= Nb) continue;
            float um = us[col], bb = bias[col];
            #pragma unroll
            for (int i = 0; i < 4; ++i)
                #pragma unroll
                for (int q = 0; q < 4; ++q) {
                    int row = bm + i * 16 + rq + q;
                    if (row < Mlim)
                        C[(size_t)row * ldc + col] = f2bf((acc[i][j][q] + bb) * um);
                }
        }
    } else {
        // ---- LDS-transposed epilogue: reuse As as a [16][260] f32 tile ----
        float* C = (float*)Cout;
        float* epi = reinterpret_cast<float*>(As);       // 16*260*4 = 16640 B
        float bb[4];
        #pragma unroll
        for (int j = 0; j < 4; ++j) {
            int col = bn + wc + j * 16 + rl;
            bb[j] = (col < Nb) ? bias[col] : 0.f;
        }
        const int r16 = tid >> 6, c4 = (tid & 63) << 2;  // reader coords
        #pragma unroll
        for (int i = 0; i < 4; ++i) {                    // 16-row pass
            __syncthreads();   // As/epi free (prev pass read or main loop done)
            #pragma unroll
            for (int j = 0; j < 4; ++j) {
                int colL = wc + j * 16 + rl;
                #pragma unroll
                for (int q = 0; q < 4; ++q) {
                    float v = acc[i][j][q] + bb[j];
                    epi[(rq + q) * 260 + colL] = 1.f / (1.f + __expf(-v));
                }
            }
            __syncthreads();
            #pragma unroll
            for (int r4 = 0; r4 < 4; ++r4) {
                int rowL = (r4 << 2) + r16;
                int grow = bm + (i << 4) + rowL;
                f32x4 v = *reinterpret_cast<const f32x4*>(&epi[rowL * 260 + c4]);
                if (grow < Mlim) {
                    if (bn + 256 <= Nb) {                // full-width fast path
                        __builtin_nontemporal_store(v,
                            reinterpret_cast<f32x4*>(&C[(size_t)grow * ldc + bn + c4]));
                    } else {                             // ragged right edge
                        #pragma unroll
                        for (int e = 0; e < 4; ++e)
                            if (bn + c4 + e < Nb)
                                __builtin_nontemporal_store(v[e],
                                    &C[(size_t)grow * ldc + bn + c4 + e]);
                    }
                }
            }
        }
    }
}

// ---------------------------------------------------------------- launcher
extern "C" void kernel_launch(void* const* d_in, const int* in_sizes, int n_in,
                              void* d_out, int out_size, void* d_ws, size_t ws_size,
                              hipStream_t stream)
{
    const int*   tim       = (const int*)  d_in[0];
    const float* app       = (const float*)d_in[1];
    const int*   uid       = (const int*)  d_in[3];
    const int*   ptim      = (const int*)  d_in[4];
    const float* emb_tim_w = (const float*)d_in[5];
    const float* emb_uid_w = (const float*)d_in[6];
    const float* emb_app_w = (const float*)d_in[7];
    const float* attn_W    = (const float*)d_in[8];
    const float* attn_b    = (const float*)d_in[9];
    const float* attn_fc_w = (const float*)d_in[10];
    const float* attn_fc_b = (const float*)d_in[11];
    const float* dec_w     = (const float*)d_in[12];
    const float* dec_b     = (const float*)d_in[13];
    float* out = (float*)d_out;

    char* w = (char*)d_ws;
    size_t o = 0;
    auto alloc = [&](size_t bytes) { char* p = w + o; o = (o + bytes + 511) & ~(size_t)511; return p; };
    unsigned short* xb      = (unsigned short*)alloc((size_t)S * DIN * 2);
    unsigned short* pooledb = (unsigned short*)alloc((size_t)S * DIN * 2);
    unsigned short* yb      = (unsigned short*)alloc((size_t)S * DIN * 2);
    float*          s       = (float*)        alloc((size_t)S * 4);
    unsigned short* Bpp     = (unsigned short*)alloc((size_t)EAPP * KPAD * 2);
    unsigned short* decb    = (unsigned short*)alloc((size_t)NDEC * DIN * 2);
    unsigned short* fcb     = (unsigned short*)alloc((size_t)EAPP * DIN * 2);
    float*          part    = (float*)        alloc((size_t)NSK * S * EAPP * 4);

    // independent weight prep
    k_cvt_bf16<<<(NDEC * DIN / 8 + 255) / 256, 256, 0, stream>>>(dec_w, decb, NDEC * DIN / 8);
    k_cvt_bf16<<<(EAPP * DIN / 8 + 255) / 256, 256, 0, stream>>>(attn_fc_w, fcb, EAPP * DIN / 8);
    dim3 gT(KPAD / 64, EAPP / 64);
    k_bake_appw<<<gT, 256, 0, stream>>>(emb_app_w, Bpp);
    k_embed_tim<<<S / 4, 256, 0, stream>>>(tim, emb_tim_w, xb);

    // x[:,0:256] = app @ emb_app_w   (3-buffer counted-vmcnt pipeline, 3/CU)
    dim3 gApp(NSK, S / 32);
    k_app<<<gApp, 256, 0, stream>>>(app, Bpp, part);
    k_reduce_app<<<S * 64 / 256, 256, 0, stream>>>(part, app, Bpp, xb);

    // attention
    k_score<<<S / 4, 256, 0, stream>>>(xb, attn_W, s);
    k_pooled<<<NR, DIN, 0, stream>>>(xb, s, attn_b, pooledb);
    k_embed_ptim<<<S / 4, 256, 0, stream>>>(ptim, emb_tim_w, yb);

    // y[:,0:256] = (pooled @ fc^T + b) * uid_emb     (64 blocks)
    k_nt320<1><<<64, 256, 0, stream>>>(pooledb, fcb, EAPP, S,
                                       attn_fc_b, emb_uid_w, uid, yb, DIN);
    // score = sigmoid(y @ dec_w^T + dec_b)           (2560 blocks)
    k_nt320<2><<<40 * 64, 256, 0, stream>>>(yb, decb, NDEC, NR,
                                            dec_b, nullptr, nullptr, out, NDEC);
}

// Round 18
// 219.314 us; speedup vs baseline: 1.1339x; 1.1339x over previous
//
#include <hip/hip_runtime.h>

typedef __attribute__((ext_vector_type(8))) short  bf16x8;
typedef __attribute__((ext_vector_type(8))) unsigned short u16x8;
typedef __attribute__((ext_vector_type(4))) float  f32x4;

constexpr int S    = 4096;
constexpr int NR   = 4093;
constexpr int KAPP = 10000;
constexpr int EAPP = 256;
constexpr int ETIM = 64;
constexpr int DIN  = 320;
constexpr int NDEC = 10000;
constexpr int NSK  = 8;           // split-K slices for app GEMM (== XCD count)
constexpr int KCH  = 1280;        // k-chunk per slice (40 uniform steps)
constexpr int KPAD = NSK * KCH;   // 10240, Bp zero-padded past 10000
constexpr int NS   = KCH / 32;    // 40 K-steps per block

__device__ inline unsigned short f2bf(float f) {
    unsigned u = __float_as_uint(f);
    u += 0x7fffu + ((u >> 16) & 1u);      // RTN-even
    return (unsigned short)(u >> 16);
}
__device__ inline float bf2f(unsigned short h) {
    return __uint_as_float(((unsigned)h) << 16);
}
__device__ inline u16x8 pack8(f32x4 a, f32x4 b) {
    u16x8 v;
    v[0]=f2bf(a.x); v[1]=f2bf(a.y); v[2]=f2bf(a.z); v[3]=f2bf(a.w);
    v[4]=f2bf(b.x); v[5]=f2bf(b.y); v[6]=f2bf(b.z); v[7]=f2bf(b.w);
    return v;
}
__device__ inline bf16x8 as_bf(u16x8 v) {
    union { u16x8 u; bf16x8 b; } c; c.u = v; return c.b;
}

// -------------------------------------------------- fp32 -> bf16 bulk convert
__global__ __launch_bounds__(256) void k_cvt_bf16(
    const float* __restrict__ in, unsigned short* __restrict__ out, int n8)
{
    int id = blockIdx.x * 256 + threadIdx.x;
    if (id >= n8) return;
    const float* p = in + (size_t)id * 8;
    f32x4 a = *reinterpret_cast<const f32x4*>(p);
    f32x4 b = *reinterpret_cast<const f32x4*>(p + 4);
    *reinterpret_cast<u16x8*>(out + (size_t)id * 8) = pack8(a, b);
}

// ------------------------------- emb_app_w [10000][256] -> Bp bf16 [256][10240]
__global__ __launch_bounds__(256) void k_transpose_appw(
    const float* __restrict__ B, unsigned short* __restrict__ Bp)
{
    __shared__ float T[64][68];
    const int kt = blockIdx.x * 64, nt = blockIdx.y * 64;
    const int tid = threadIdx.x;
    #pragma unroll
    for (int i = 0; i < 4; ++i) {
        int c = tid + (i << 8);
        int k = c >> 4, n4 = (c & 15) << 2;
        f32x4 v = {0.f, 0.f, 0.f, 0.f};
        if (kt + k < KAPP)
            v = *reinterpret_cast<const f32x4*>(&B[(size_t)(kt + k) * EAPP + nt + n4]);
        *reinterpret_cast<f32x4*>(&T[k][n4]) = v;
    }
    __syncthreads();
    #pragma unroll
    for (int i = 0; i < 2; ++i) {
        int c = tid + (i << 8);
        int n = c >> 3, ko = (c & 7) << 3;
        u16x8 v;
        #pragma unroll
        for (int j = 0; j < 8; ++j) v[j] = f2bf(T[ko + j][n]);
        *reinterpret_cast<u16x8*>(&Bp[(size_t)(nt + n) * KPAD + kt + ko]) = v;
    }
}

// ---------------------------------------------------------------- embeddings
__global__ __launch_bounds__(256) void k_embed_tim(
    const int* __restrict__ tim, const float* __restrict__ emb_tim,
    unsigned short* __restrict__ xb)
{
    int r = blockIdx.x * 4 + (threadIdx.x >> 6);
    int e = threadIdx.x & 63;
    xb[(size_t)r * DIN + EAPP + e] = f2bf(emb_tim[tim[r] * ETIM + e]);
}
__global__ __launch_bounds__(256) void k_embed_ptim(
    const int* __restrict__ ptim, const float* __restrict__ emb_tim,
    unsigned short* __restrict__ yb)
{
    int r = blockIdx.x * 4 + (threadIdx.x >> 6);
    int e = threadIdx.x & 63;
    if (r < NR) yb[(size_t)r * DIN + EAPP + e] = f2bf(emb_tim[ptim[r] * ETIM + e]);
}

// ---------- app GEMM: split-K x8 (XCD-pinned), tile 32x256, LDS dbuf,
// ---------- chunked layout [ck16B][row][16B], ONE barrier/step, 4 blocks/CU
__global__ __launch_bounds__(256, 4) void k_app(
    const float* __restrict__ A, const unsigned short* __restrict__ Bp,
    float* __restrict__ part)
{
    __shared__ unsigned short As[2][4 * 32 * 8];    // 4 KB  ((ck*32+row)*8)
    __shared__ unsigned short Bs[2][4 * 256 * 8];   // 32 KB ((ck*256+row)*8)
    const int tid = threadIdx.x, lane = tid & 63, w = tid >> 6;
    const int ks = blockIdx.x, bm = blockIdx.y << 5;   // flat%8==ks -> XCD-pinned
    const int wc = w << 6, rl = lane & 15, kq = lane >> 4;   // kq in 0..3
    const int k0 = ks * KCH;
    const int arow = tid >> 2, ac = tid & 3;          // A-stage (tid<128): row, ck

    u16x8 ra, rb[4];
    auto gload = [&](int step) {
        const int kt = k0 + (step << 5);
        if (tid < 128) {
            const int k = kt + (ac << 3);
            u16x8 v = {0,0,0,0,0,0,0,0};
            if (k < KAPP) {                           // zero-fill past 10000
                const float* p = &A[(size_t)(bm + arow) * KAPP + k];
                v = pack8(*reinterpret_cast<const f32x4*>(p),
                          *reinterpret_cast<const f32x4*>(p + 4));
            }
            ra = v;
        }
        #pragma unroll
        for (int i = 0; i < 4; ++i) {
            int c = tid + (i << 8);
            int row = c >> 2, ck = c & 3;
            rb[i] = *reinterpret_cast<const u16x8*>(
                &Bp[(size_t)row * KPAD + kt + (ck << 3)]);
        }
    };
    auto swrite = [&](int b) {
        if (tid < 128)
            *reinterpret_cast<u16x8*>(&As[b][((ac << 5) + arow) << 3]) = ra;
        #pragma unroll
        for (int i = 0; i < 4; ++i) {
            int c = tid + (i << 8);
            int row = c >> 2, ck = c & 3;
            *reinterpret_cast<u16x8*>(&Bs[b][((ck << 8) + row) << 3]) = rb[i];
        }
    };

    f32x4 acc[2][4];
    #pragma unroll
    for (int i = 0; i < 2; ++i)
        #pragma unroll
        for (int j = 0; j < 4; ++j) acc[i][j] = (f32x4){0.f, 0.f, 0.f, 0.f};

    gload(0); swrite(0); __syncthreads();
    for (int t = 0; t < NS; ++t) {
        const int cur = t & 1;
        const bool more = (t + 1 < NS);
        if (more) gload(t + 1);                       // issue next-step loads
        bf16x8 af[2], bfr[4];
        #pragma unroll
        for (int i = 0; i < 2; ++i)
            af[i] = *reinterpret_cast<const bf16x8*>(
                &As[cur][((kq << 5) + i * 16 + rl) << 3]);
        #pragma unroll
        for (int j = 0; j < 4; ++j)
            bfr[j] = *reinterpret_cast<const bf16x8*>(
                &Bs[cur][((kq << 8) + wc + j * 16 + rl) << 3]);
        #pragma unroll
        for (int i = 0; i < 2; ++i)
            #pragma unroll
            for (int j = 0; j < 4; ++j)
                acc[i][j] = __builtin_amdgcn_mfma_f32_16x16x32_bf16(
                    af[i], bfr[j], acc[i][j], 0, 0, 0);
        if (more) swrite(cur ^ 1);                    // write OTHER buffer
        __syncthreads();                              // one barrier per step
    }

    float* P = part + ((size_t)ks * S + bm) * EAPP;
    const int rq = kq << 2;
    #pragma unroll
    for (int i = 0; i < 2; ++i)
        #pragma unroll
        for (int j = 0; j < 4; ++j) {
            int col = wc + j * 16 + rl;
            #pragma unroll
            for (int q = 0; q < 4; ++q)
                __builtin_nontemporal_store(acc[i][j][q],
                    &P[(size_t)(i * 16 + rq + q) * EAPP + col]);
        }
}

// ----------------------------------- reduce split-K partials -> xb[:,0:256]
__global__ __launch_bounds__(256) void k_reduce_app(
    const float* __restrict__ part, unsigned short* __restrict__ xb)
{
    int id = blockIdx.x * 256 + threadIdx.x;   // 262144 = 4096*64
    int row = id >> 6, c4 = (id & 63) << 2;
    f32x4 s = {0.f, 0.f, 0.f, 0.f};
    #pragma unroll
    for (int sl = 0; sl < NSK; ++sl) {
        f32x4 v = __builtin_nontemporal_load(reinterpret_cast<const f32x4*>(
            &part[((size_t)sl * S + row) * EAPP + c4]));
        s.x += v.x; s.y += v.y; s.z += v.z; s.w += v.w;
    }
    unsigned short* o = &xb[(size_t)row * DIN + c4];
    o[0] = f2bf(s.x); o[1] = f2bf(s.y); o[2] = f2bf(s.z); o[3] = f2bf(s.w);
}

// ------------------------------------------------- attention score + pooling
__global__ __launch_bounds__(256) void k_score(
    const unsigned short* __restrict__ xb, const float* __restrict__ W,
    float* __restrict__ s)
{
    int wv = threadIdx.x >> 6, lane = threadIdx.x & 63;
    int m = blockIdx.x * 4 + wv;
    float sum = 0.f;
    #pragma unroll
    for (int i = 0; i < 5; ++i) {
        int k = lane + (i << 6);
        sum += bf2f(xb[(size_t)m * DIN + k]) * W[k];
    }
    #pragma unroll
    for (int off = 32; off; off >>= 1) sum += __shfl_down(sum, off);
    if (lane == 0) s[m] = sum;
}

__global__ void k_pooled(
    const unsigned short* __restrict__ xb, const float* __restrict__ s,
    const float* __restrict__ attn_b, unsigned short* __restrict__ pooledb)
{
    int n = blockIdx.x, d = threadIdx.x;
    float h[4], den = 0.f;
    #pragma unroll
    for (int f = 0; f < 4; ++f) {
        h[f] = tanhf(s[n + f] + attn_b[f]);
        den += fabsf(h[f]);
    }
    float inv = 1.f / den, p = 0.f;
    #pragma unroll
    for (int f = 0; f < 4; ++f)
        p = fmaf(h[f] * inv, bf2f(xb[(size_t)(n + f) * DIN + d]), p);
    pooledb[(size_t)n * DIN + d] = f2bf(p);
}

// ------------------- NT GEMM, K=320: A staged ONCE in chunked LDS (40960 B),
// ------------------- B streamed with depth-2 prefetch, bn-FASTEST block order
// ------------------- (concurrent blocks per XCD cover one contiguous output
// ------------------- window -> DRAM-friendly writes), nontemporal stores.
// EPI 1: (acc+bias[j])*uid_emb[j] -> bf16. EPI 2: sigmoid -> f32 (LDS-coalesced).
template<int EPI>
__global__ __launch_bounds__(256, 4) void k_nt320(
    const unsigned short* __restrict__ A, const unsigned short* __restrict__ B,
    int Nb, int Mlim,
    const float* __restrict__ bias,
    const float* __restrict__ emb_uid, const int* __restrict__ uid,
    void* __restrict__ Cout, int ldc)
{
    __shared__ unsigned short As[40 * 64 * 8];     // ((ck*64+row)*8), 40960 B
    const int tid = threadIdx.x, lane = tid & 63, w = tid >> 6;
    const int qx = gridDim.x >> 3;                 // nwg % 8 == 0 always here
    const int swz = (blockIdx.x & 7) * qx + (blockIdx.x >> 3);
    const int nbn = (Nb + 255) >> 8;               // bn-groups (dec: 40, fc: 1)
    const int bm = (swz / nbn) << 6, bn = (swz % nbn) << 8;   // bn FASTEST
    const int rl = lane & 15, kq = lane >> 4;
    const int wc = w << 6;

    {   // stage A-tile (64 x 320 bf16 = 40 KB) once, chunked layout
        const int row = tid >> 2, c0 = tid & 3;
        const unsigned short* src = A + (size_t)(bm + row) * DIN;
        #pragma unroll
        for (int t = 0; t < 10; ++t) {
            int ck = c0 + (t << 2);
            *reinterpret_cast<u16x8*>(&As[((ck << 6) + row) << 3]) =
                *reinterpret_cast<const u16x8*>(src + (ck << 3));
        }
    }
    __syncthreads();

    f32x4 acc[4][4];
    #pragma unroll
    for (int i = 0; i < 4; ++i)
        #pragma unroll
        for (int j = 0; j < 4; ++j) acc[i][j] = (f32x4){0.f, 0.f, 0.f, 0.f};

    u16x8 b0[4], b1[4];
#define LOADB(DST, KSN) do {                                                    \
    const int kg_ = ((KSN) << 5) + (kq << 3);                                   \
    _Pragma("unroll")                                                           \
    for (int j = 0; j < 4; ++j) {                                               \
        int brow = bn + wc + j * 16 + rl;                                       \
        u16x8 v_ = {0,0,0,0,0,0,0,0};                                           \
        if (brow < Nb)                                                          \
            v_ = *reinterpret_cast<const u16x8*>(&B[(size_t)brow * DIN + kg_]); \
        DST[j] = v_;                                                            \
    }                                                                           \
} while (0)

#define STEPNT(BARR, KSN) do {                                                  \
    const int ckb_ = (((KSN) << 2) + kq) << 6;                                  \
    bf16x8 af_[4];                                                              \
    _Pragma("unroll")                                                           \
    for (int i = 0; i < 4; ++i)                                                 \
        af_[i] = *reinterpret_cast<const bf16x8*>(                              \
            &As[(ckb_ + i * 16 + rl) << 3]);                                    \
    _Pragma("unroll")                                                           \
    for (int i = 0; i < 4; ++i)                                                 \
        _Pragma("unroll")                                                       \
        for (int j = 0; j < 4; ++j)                                             \
            acc[i][j] = __builtin_amdgcn_mfma_f32_16x16x32_bf16(                \
                af_[i], as_bf(BARR[j]), acc[i][j], 0, 0, 0);                     \
} while (0)

    LOADB(b0, 0);
    LOADB(b1, 1);
    #pragma unroll
    for (int p = 0; p < 5; ++p) {
        STEPNT(b0, 2 * p);
        if (2 * p + 2 < 10) LOADB(b0, 2 * p + 2);
        STEPNT(b1, 2 * p + 1);
        if (2 * p + 3 < 10) LOADB(b1, 2 * p + 3);
    }
#undef LOADB
#undef STEPNT

    const int rq = kq << 2;
    if (EPI == 1) {
        unsigned short* C = (unsigned short*)Cout;
        const float* us = emb_uid + (size_t)uid[0] * EAPP;
        #pragma unroll
        for (int j = 0; j < 4; ++j) {
            int col = bn + wc + j * 16 + rl;
            if (col >= Nb) continue;
            float um = us[col], bb = bias[col];
            #pragma unroll
            for (int i = 0; i < 4; ++i)
                #pragma unroll
                for (int q = 0; q < 4; ++q) {
                    int row = bm + i * 16 + rq + q;
                    if (row < Mlim)
                        C[(size_t)row * ldc + col] = f2bf((acc[i][j][q] + bb) * um);
                }
        }
    } else {
        // ---- LDS-transposed epilogue: reuse As as a [16][260] f32 tile ----
        float* C = (float*)Cout;
        float* epi = reinterpret_cast<float*>(As);       // 16*260*4 = 16640 B
        float bb[4];
        #pragma unroll
        for (int j = 0; j < 4; ++j) {
            int col = bn + wc + j * 16 + rl;
            bb[j] = (col < Nb) ? bias[col] : 0.f;
        }
        const int r16 = tid >> 6, c4 = (tid & 63) << 2;  // reader coords
        #pragma unroll
        for (int i = 0; i < 4; ++i) {                    // 16-row pass
            __syncthreads();   // As/epi free (prev pass read or main loop done)
            #pragma unroll
            for (int j = 0; j < 4; ++j) {
                int colL = wc + j * 16 + rl;
                #pragma unroll
                for (int q = 0; q < 4; ++q) {
                    float v = acc[i][j][q] + bb[j];
                    epi[(rq + q) * 260 + colL] = 1.f / (1.f + __expf(-v));
                }
            }
            __syncthreads();
            #pragma unroll
            for (int r4 = 0; r4 < 4; ++r4) {
                int rowL = (r4 << 2) + r16;
                int grow = bm + (i << 4) + rowL;
                f32x4 v = *reinterpret_cast<const f32x4*>(&epi[rowL * 260 + c4]);
                if (grow < Mlim) {
                    if (bn + 256 <= Nb) {                // full-width fast path
                        __builtin_nontemporal_store(v,
                            reinterpret_cast<f32x4*>(&C[(size_t)grow * ldc + bn + c4]));
                    } else {                             // ragged right edge
                        #pragma unroll
                        for (int e = 0; e < 4; ++e)
                            if (bn + c4 + e < Nb)
                                __builtin_nontemporal_store(v[e],
                                    &C[(size_t)grow * ldc + bn + c4 + e]);
                    }
                }
            }
        }
    }
}

// ---------------------------------------------------------------- launcher
extern "C" void kernel_launch(void* const* d_in, const int* in_sizes, int n_in,
                              void* d_out, int out_size, void* d_ws, size_t ws_size,
                              hipStream_t stream)
{
    const int*   tim       = (const int*)  d_in[0];
    const float* app       = (const float*)d_in[1];
    const int*   uid       = (const int*)  d_in[3];
    const int*   ptim      = (const int*)  d_in[4];
    const float* emb_tim_w = (const float*)d_in[5];
    const float* emb_uid_w = (const float*)d_in[6];
    const float* emb_app_w = (const float*)d_in[7];
    const float* attn_W    = (const float*)d_in[8];
    const float* attn_b    = (const float*)d_in[9];
    const float* attn_fc_w = (const float*)d_in[10];
    const float* attn_fc_b = (const float*)d_in[11];
    const float* dec_w     = (const float*)d_in[12];
    const float* dec_b     = (const float*)d_in[13];
    float* out = (float*)d_out;

    char* w = (char*)d_ws;
    size_t o = 0;
    auto alloc = [&](size_t bytes) { char* p = w + o; o = (o + bytes + 511) & ~(size_t)511; return p; };
    unsigned short* xb      = (unsigned short*)alloc((size_t)S * DIN * 2);
    unsigned short* pooledb = (unsigned short*)alloc((size_t)S * DIN * 2);
    unsigned short* yb      = (unsigned short*)alloc((size_t)S * DIN * 2);
    float*          s       = (float*)        alloc((size_t)S * 4);
    unsigned short* Bp      = (unsigned short*)alloc((size_t)EAPP * KPAD * 2);
    unsigned short* decb    = (unsigned short*)alloc((size_t)NDEC * DIN * 2);
    unsigned short* fcb     = (unsigned short*)alloc((size_t)EAPP * DIN * 2);
    float*          part    = (float*)        alloc((size_t)NSK * S * EAPP * 4);

    // independent weight prep
    k_cvt_bf16<<<(NDEC * DIN / 8 + 255) / 256, 256, 0, stream>>>(dec_w, decb, NDEC * DIN / 8);
    k_cvt_bf16<<<(EAPP * DIN / 8 + 255) / 256, 256, 0, stream>>>(attn_fc_w, fcb, EAPP * DIN / 8);
    dim3 gT(KPAD / 64, EAPP / 64);
    k_transpose_appw<<<gT, 256, 0, stream>>>(emb_app_w, Bp);
    k_embed_tim<<<S / 4, 256, 0, stream>>>(tim, emb_tim_w, xb);

    // x[:,0:256] = app @ emb_app_w   (split-K x8 XCD-pinned, 32-row tiles)
    dim3 gApp(NSK, S / 32);
    k_app<<<gApp, 256, 0, stream>>>(app, Bp, part);
    k_reduce_app<<<S * 64 / 256, 256, 0, stream>>>(part, xb);

    // attention
    k_score<<<S / 4, 256, 0, stream>>>(xb, attn_W, s);
    k_pooled<<<NR, DIN, 0, stream>>>(xb, s, attn_b, pooledb);
    k_embed_ptim<<<S / 4, 256, 0, stream>>>(ptim, emb_tim_w, yb);

    // y[:,0:256] = (pooled @ fc^T + b) * uid_emb     (64 blocks)
    k_nt320<1><<<64, 256, 0, stream>>>(pooledb, fcb, EAPP, S,
                                       attn_fc_b, emb_uid_w, uid, yb, DIN);
    // score = sigmoid(y @ dec_w^T + dec_b)           (2560 blocks)
    k_nt320<2><<<40 * 64, 256, 0, stream>>>(yb, decb, NDEC, NR,
                                            dec_b, nullptr, nullptr, out, NDEC);
}